// Round 7
// baseline (376.120 us; speedup 1.0000x reference)
//
#include <hip/hip_runtime.h>
#include <hip/hip_bf16.h>
#include <math.h>
#include <stddef.h>

#define NN 8192
#define NEG_SLOPE 0.2f

typedef _Float16 h8 __attribute__((ext_vector_type(8)));
typedef __attribute__((ext_vector_type(4))) float f32x4;

__device__ __forceinline__ float lrelu(float x) { return x > 0.f ? x : NEG_SLOPE * x; }
__device__ __forceinline__ float sigf(float x) { return 1.f / (1.f + __expf(-x)); }

__device__ __forceinline__ unsigned short f16b(float x) {
    _Float16 h = (_Float16)x;
    unsigned short u;
    __builtin_memcpy(&u, &h, 2);
    return u;
}
__device__ __forceinline__ float f16f(unsigned short u) {
    _Float16 h;
    __builtin_memcpy(&h, &u, 2);
    return (float)h;
}
__device__ __forceinline__ void splith(float x, unsigned short& hu, unsigned short& lu) {
    _Float16 h = (_Float16)x;
    float hf = (float)h;
    _Float16 l = (_Float16)(x - hf);
    __builtin_memcpy(&hu, &h, 2);
    __builtin_memcpy(&lu, &l, 2);
}
__device__ __forceinline__ float2 unpkh(unsigned int v) {
    float2 r;
    r.x = f16f((unsigned short)(v & 0xffffu));
    r.y = f16f((unsigned short)(v >> 16));
    return r;
}
__device__ __forceinline__ unsigned int packh(float a, float b) {
    return (unsigned int)f16b(a) | ((unsigned int)f16b(b) << 16);
}
// accumulate 8 fp16 (uint4) * w into a[0..7]
__device__ __forceinline__ void acc8(float* a, uint4 v, float w) {
    float2 p;
    p = unpkh(v.x); a[0] += w * p.x; a[1] += w * p.y;
    p = unpkh(v.y); a[2] += w * p.x; a[3] += w * p.y;
    p = unpkh(v.z); a[4] += w * p.x; a[5] += w * p.y;
    p = unpkh(v.w); a[6] += w * p.x; a[7] += w * p.y;
}

// async global->LDS, 16B per lane; lds base must be wave-uniform
__device__ __forceinline__ void gll16(const unsigned short* g, unsigned short* l) {
    __builtin_amdgcn_global_load_lds(
        (const __attribute__((address_space(1))) unsigned int*)g,
        (__attribute__((address_space(3))) unsigned int*)l, 16, 0, 0);
}

// ---------------- CSR build ----------------
__global__ void k_zero(int* __restrict__ p, int n) {
    int i = blockIdx.x * blockDim.x + threadIdx.x;
    if (i < n) p[i] = 0;
}
__global__ void k_count(const int* __restrict__ dst, int* __restrict__ cnt, int E) {
    int i = blockIdx.x * blockDim.x + threadIdx.x;
    if (i < E) atomicAdd(&cnt[dst[i]], 1);
}
__global__ void k_dinv(const int* __restrict__ cnt, float* __restrict__ dinv) {
    int i = blockIdx.x * blockDim.x + threadIdx.x;
    if (i < NN) dinv[i] = rsqrtf((float)(cnt[i] + 1));
}
__global__ void k_scan(const int* __restrict__ cnt, int* __restrict__ row_ptr) {
    __shared__ int part[1024];
    int t = threadIdx.x;
    int base = t * 8;
    int loc[8];
    int s = 0;
    #pragma unroll
    for (int j = 0; j < 8; ++j) { loc[j] = s; s += cnt[base + j]; }
    part[t] = s;
    __syncthreads();
    for (int off = 1; off < 1024; off <<= 1) {
        int v = (t >= off) ? part[t - off] : 0;
        __syncthreads();
        part[t] += v;
        __syncthreads();
    }
    int pre = (t == 0) ? 0 : part[t - 1];
    #pragma unroll
    for (int j = 0; j < 8; ++j) row_ptr[base + j] = pre + loc[j];
    if (t == 1023) row_ptr[NN] = part[1023];
}
__global__ void k_fill(const int* __restrict__ src, const int* __restrict__ dst,
                       const int* __restrict__ row_ptr, int* __restrict__ cursor,
                       int* __restrict__ csr_src, int E) {
    int i = blockIdx.x * blockDim.x + threadIdx.x;
    if (i < E) {
        int d = dst[i];
        csr_src[row_ptr[d] + atomicAdd(&cursor[d], 1)] = src[i];
    }
}

// ---------------- x fp32 -> fp16 ----------------
__global__ void k_cvt_x(const float* __restrict__ x, unsigned short* __restrict__ xh) {
    int i = blockIdx.x * 256 + threadIdx.x;     // over NN*512/4
    int m = i >> 7, k4 = (i & 127) * 4;
    float4 v = *(const float4*)(x + (size_t)m * 512 + k4);
    ushort4 o;
    o.x = f16b(v.x); o.y = f16b(v.y); o.z = f16b(v.z); o.w = f16b(v.w);
    *(ushort4*)&xh[(size_t)m * 512 + k4] = o;
}

// W[z] [K,N] fp32 -> Wt fp16 rows (noff + z*noff_z + n) of length K
__global__ void k_wT(const float* __restrict__ W, unsigned short* __restrict__ Wt,
                     int K, int N, size_t wt_z_stride, int noff, int noff_z) {
    int b = blockIdx.z;
    W += (size_t)b * K * N;
    Wt += (size_t)b * wt_z_stride;
    int rowbase = noff + b * noff_z;
    int k0 = blockIdx.x * 32, n0 = blockIdx.y * 32;
    __shared__ float tl[32][33];
    int tid = threadIdx.x;
    int r = tid >> 5, cc = tid & 31;
    #pragma unroll
    for (int c = 0; c < 4; ++c)
        tl[r + c * 8][cc] = W[(size_t)(k0 + r + c * 8) * N + n0 + cc];
    __syncthreads();
    #pragma unroll
    for (int c = 0; c < 4; ++c) {
        int n = r + c * 8, k = cc;
        Wt[(size_t)(rowbase + n0 + n) * K + k0 + k] = f16b(tl[k][n]);
    }
}

// ---------------- fp16 MFMA GEMM, global_load_lds staging ----------------
template <int ROWS>
__device__ __forceinline__ void stage(const unsigned short* __restrict__ gbase, int lda,
                                      unsigned short* lds, int wid, int lane) {
    #pragma unroll
    for (int c = 0; c < ROWS / 32; ++c) {
        int chunk = c * 4 + wid;                // 1KB chunks
        int row = chunk * 8 + (lane >> 3);
        int g = (lane & 7) ^ (row & 7);
        gll16(gbase + (size_t)row * lda + g * 8, lds + chunk * 512);
    }
}
__device__ __forceinline__ h8 fragrh(const unsigned short* lds, int row, int kg) {
    return *(const h8*)(lds + row * 64 + ((kg ^ (row & 7)) * 8));
}

template <int TERMS, int EPI>   // EPI: 0 fp32, 1 fp32+sigmoid, 2 fp16
__global__ __launch_bounds__(256) void k_gemm2(
    const unsigned short* __restrict__ A2, size_t azs, int lda,
    const unsigned short* __restrict__ B2, size_t bzs, int ldb,
    void* __restrict__ Cv, size_t czs, int ldc, int K) {
    __shared__ __align__(16) unsigned short sAh[128 * 64];
    __shared__ __align__(16) unsigned short sBh[64 * 64];
    __shared__ __align__(16) unsigned short sAl[(TERMS == 3) ? 128 * 64 : 8];
    __shared__ __align__(16) unsigned short sBl[(TERMS == 3) ? 64 * 64 : 8];
    const int tid = threadIdx.x;
    const int wid = tid >> 6, lane = tid & 63;
    const int wr = wid >> 1, wc = wid & 1;
    const int lr = lane & 15, lg = lane >> 4;
    const int m0 = blockIdx.x * 128, n0 = blockIdx.y * 64;
    const int z = blockIdx.z;
    A2 += (size_t)z * azs;
    B2 += (size_t)z * bzs;

    const f32x4 zero4 = {0.f, 0.f, 0.f, 0.f};
    f32x4 acc[4][2];
    #pragma unroll
    for (int m = 0; m < 4; ++m)
        #pragma unroll
        for (int n = 0; n < 2; ++n) acc[m][n] = zero4;

    for (int k0 = 0; k0 < K; k0 += 64) {
        stage<128>(A2 + (size_t)m0 * lda + k0, lda, sAh, wid, lane);
        stage<64> (B2 + (size_t)n0 * ldb + k0, ldb, sBh, wid, lane);
        if (TERMS == 3) {
            stage<128>(A2 + (size_t)m0 * lda + K + k0, lda, sAl, wid, lane);
            stage<64> (B2 + (size_t)n0 * ldb + K + k0, ldb, sBl, wid, lane);
        }
        __syncthreads();
        #pragma unroll
        for (int ks = 0; ks < 2; ++ks) {
            const int kg = ks * 4 + lg;
            h8 ah[4], al[4], bh[2], bl[2];
            #pragma unroll
            for (int m = 0; m < 4; ++m) {
                int row = wr * 64 + m * 16 + lr;
                ah[m] = fragrh(sAh, row, kg);
                if (TERMS == 3) al[m] = fragrh(sAl, row, kg);
            }
            #pragma unroll
            for (int n = 0; n < 2; ++n) {
                int row = wc * 32 + n * 16 + lr;
                bh[n] = fragrh(sBh, row, kg);
                if (TERMS == 3) bl[n] = fragrh(sBl, row, kg);
            }
            #pragma unroll
            for (int m = 0; m < 4; ++m)
                #pragma unroll
                for (int n = 0; n < 2; ++n) {
                    acc[m][n] = __builtin_amdgcn_mfma_f32_16x16x32_f16(ah[m], bh[n], acc[m][n], 0, 0, 0);
                    if (TERMS == 3) {
                        acc[m][n] = __builtin_amdgcn_mfma_f32_16x16x32_f16(al[m], bh[n], acc[m][n], 0, 0, 0);
                        acc[m][n] = __builtin_amdgcn_mfma_f32_16x16x32_f16(ah[m], bl[n], acc[m][n], 0, 0, 0);
                    }
                }
        }
        __syncthreads();
    }
    #pragma unroll
    for (int m = 0; m < 4; ++m)
        #pragma unroll
        for (int n = 0; n < 2; ++n)
            #pragma unroll
            for (int j = 0; j < 4; ++j) {
                int row = m0 + wr * 64 + m * 16 + lg * 4 + j;
                int col = n0 + wc * 32 + n * 16 + lr;
                float o = acc[m][n][j];
                if (EPI == 1) {
                    ((float*)Cv + (size_t)z * czs)[(size_t)row * ldc + col] = sigf(o);
                } else if (EPI == 2) {
                    ((unsigned short*)Cv + (size_t)z * czs)[(size_t)row * ldc + col] = f16b(o);
                } else {
                    ((float*)Cv + (size_t)z * czs)[(size_t)row * ldc + col] = o;
                }
            }
}

// ---------------- GCN aggregates: 256 thr = 8 edge-groups x 32 lanes (uint4 row) -----
// RELU_BIAS=1: out = relu(dd*sum + b); else out = dd*sum
template <int RELU_BIAS>
__global__ void k_gcn_agg(const uint4* __restrict__ v4, const float* __restrict__ dinv,
                          const int* __restrict__ rp, const int* __restrict__ cs,
                          const float* __restrict__ b1, unsigned int* __restrict__ outu) {
    int d = blockIdx.x;
    int t = threadIdx.x;                         // 256
    int g = t >> 5, lr = t & 31;                 // 8 groups x 32 lanes; row = 32 uint4
    float dd = dinv[d];
    float a[8] = {0.f, 0.f, 0.f, 0.f, 0.f, 0.f, 0.f, 0.f};
    if (g == 0) {
        uint4 sv = v4[(size_t)d * 32 + lr];
        acc8(a, sv, dd);
    }
    int e0 = rp[d], e1 = rp[d + 1];
    int j = e0 + g;
    for (; j + 8 < e1; j += 16) {
        int s0 = cs[j], s1 = cs[j + 8];
        float w0 = dinv[s0], w1 = dinv[s1];
        uint4 v0 = v4[(size_t)s0 * 32 + lr];
        uint4 v1 = v4[(size_t)s1 * 32 + lr];
        acc8(a, v0, w0);
        acc8(a, v1, w1);
    }
    if (j < e1) {
        int s = cs[j];
        uint4 v = v4[(size_t)s * 32 + lr];
        acc8(a, v, dinv[s]);
    }
    __shared__ float red[8][256];
    #pragma unroll
    for (int i = 0; i < 8; ++i) red[g][lr * 8 + i] = a[i];
    __syncthreads();
    if (t < 128) {
        int c0 = 2 * t, c1 = 2 * t + 1;
        float s0 = 0.f, s1 = 0.f;
        #pragma unroll
        for (int gg = 0; gg < 8; ++gg) { s0 += red[gg][c0]; s1 += red[gg][c1]; }
        float o0, o1;
        if (RELU_BIAS) {
            o0 = fmaxf(dd * s0 + b1[c0], 0.f);
            o1 = fmaxf(dd * s1 + b1[c1], 0.f);
        } else {
            o0 = dd * s0;
            o1 = dd * s1;
        }
        outu[(size_t)d * 128 + t] = packh(o0, o1);
    }
}

// ---------------- GAT layer1 logits (z = branch) ----------------
__global__ void k_gat_log1(const unsigned int* __restrict__ xwu, const float* __restrict__ a_s,
                           const float* __restrict__ a_d, float* __restrict__ as_n,
                           float* __restrict__ ad_n) {
    int br = blockIdx.z;
    int n = blockIdx.x;
    int hd = threadIdx.x >> 6, lane = threadIdx.x & 63;   // block 192
    const unsigned int* hp = xwu + (size_t)n * 384 + br * 192 + hd * 64;
    const float* av = a_s + br * 384 + hd * 128;
    const float* dv = a_d + br * 384 + hd * 128;
    float2 f = unpkh(hp[lane]);
    float ss = f.x * av[2 * lane] + f.y * av[2 * lane + 1];
    float sd = f.x * dv[2 * lane] + f.y * dv[2 * lane + 1];
    #pragma unroll
    for (int off = 32; off; off >>= 1) {
        ss += __shfl_down(ss, off);
        sd += __shfl_down(sd, off);
    }
    if (lane == 0) {
        as_n[(size_t)br * NN * 3 + n * 3 + hd] = ss;
        ad_n[(size_t)br * NN * 3 + n * 3 + hd] = sd;
    }
}

// ---------------- GAT layer2 logits (z = branch*2 + mtype) ----------------
__global__ void k_gat_log2(const unsigned short* __restrict__ h2gb, const float* __restrict__ asmu,
                           const float* __restrict__ aslv, const float* __restrict__ admu,
                           const float* __restrict__ adlv, float* __restrict__ as_n,
                           float* __restrict__ ad_n) {
    int zz = blockIdx.z;
    int br = zz >> 1, mt = zz & 1;
    int n = blockIdx.x;
    int hd = threadIdx.x >> 6, lane = threadIdx.x & 63;   // block 192
    const unsigned short* hp = h2gb + (size_t)br * NN * 384 + (size_t)n * 384 + mt * 192 + hd * 64;
    const float* av = (mt ? aslv : asmu) + br * 192 + hd * 64;
    const float* dv = (mt ? adlv : admu) + br * 192 + hd * 64;
    float hv = f16f(hp[lane]);
    float ss = hv * av[lane];
    float sd = hv * dv[lane];
    #pragma unroll
    for (int off = 32; off; off >>= 1) {
        ss += __shfl_down(ss, off);
        sd += __shfl_down(sd, off);
    }
    if (lane == 0) {
        as_n[(size_t)zz * NN * 3 + n * 3 + hd] = ss;
        ad_n[(size_t)zz * NN * 3 + n * 3 + hd] = sd;
    }
}

// ---------------- GAT softmax weights (z batched, wave per head) ----------------
__global__ void k_gat_attn(const float* __restrict__ as_n, const float* __restrict__ ad_n,
                           const int* __restrict__ rp, const int* __restrict__ cs,
                           float* __restrict__ w_csr, float* __restrict__ w_self, int E3) {
    int zz = blockIdx.z;
    as_n += (size_t)zz * NN * 3;
    ad_n += (size_t)zz * NN * 3;
    w_csr += (size_t)zz * E3;
    w_self += (size_t)zz * NN * 3;
    int d = blockIdx.x;
    int hd = threadIdx.x >> 6, lane = threadIdx.x & 63;   // block 192
    int e0 = rp[d], e1 = rp[d + 1];
    float add = ad_n[d * 3 + hd];
    float eself = lrelu(as_n[d * 3 + hd] + add);
    float mx = eself;
    for (int j = e0 + lane; j < e1; j += 64) {
        float e = lrelu(as_n[cs[j] * 3 + hd] + add);
        w_csr[(size_t)j * 3 + hd] = e;
        mx = fmaxf(mx, e);
    }
    #pragma unroll
    for (int off = 32; off; off >>= 1) mx = fmaxf(mx, __shfl_xor(mx, off));
    float sm = (lane == 0) ? __expf(eself - mx) : 0.f;
    for (int j = e0 + lane; j < e1; j += 64)
        sm += __expf(w_csr[(size_t)j * 3 + hd] - mx);
    #pragma unroll
    for (int off = 32; off; off >>= 1) sm += __shfl_xor(sm, off);
    float inv = 1.f / sm;
    if (lane == 0) w_self[d * 3 + hd] = __expf(eself - mx) * inv;
    for (int j = e0 + lane; j < e1; j += 64)
        w_csr[(size_t)j * 3 + hd] = __expf(w_csr[(size_t)j * 3 + hd] - mx) * inv;
}

// ---------------- GAT layer1 aggregate: 384 thr = 4 groups x 96 lanes (uint4) --------
__global__ void k_gat_agg1(const uint4* __restrict__ xw4, const float* __restrict__ w_csr,
                           const float* __restrict__ w_self, const int* __restrict__ rp,
                           const int* __restrict__ cs, const float* __restrict__ b1,
                           unsigned int* __restrict__ h1su, int E3) {
    int d = blockIdx.x;
    int t = threadIdx.x;                          // 384
    int g = t / 96, lr = t - g * 96;              // 4 groups; row = 96 uint4 (768 fp16)
    int c = lr * 8;                               // fp col 0..767
    int br = c >= 384 ? 1 : 0;
    int cb = c - br * 384;
    int hd = cb >> 7;
    const float* wc = w_csr + (size_t)br * E3;
    float a[8] = {0.f, 0.f, 0.f, 0.f, 0.f, 0.f, 0.f, 0.f};
    if (g == 0) {
        float ws = w_self[(size_t)br * NN * 3 + d * 3 + hd];
        uint4 sv = xw4[(size_t)d * 96 + lr];
        acc8(a, sv, ws);
    }
    int e0 = rp[d], e1 = rp[d + 1];
    int j = e0 + g;
    for (; j + 4 < e1; j += 8) {
        int s0 = cs[j], s1 = cs[j + 4];
        float w0 = wc[(size_t)j * 3 + hd];
        float w1 = wc[(size_t)(j + 4) * 3 + hd];
        uint4 v0 = xw4[(size_t)s0 * 96 + lr];
        uint4 v1 = xw4[(size_t)s1 * 96 + lr];
        acc8(a, v0, w0);
        acc8(a, v1, w1);
    }
    if (j < e1) {
        int s = cs[j];
        float w = wc[(size_t)j * 3 + hd];
        uint4 v = xw4[(size_t)s * 96 + lr];
        acc8(a, v, w);
    }
    __shared__ float red[4][768];
    #pragma unroll
    for (int i = 0; i < 8; ++i) red[g][c + i] = a[i];
    __syncthreads();
    {
        int c0 = 2 * t, c1 = 2 * t + 1;           // 768 cols over 384 threads
        float s0 = 0.f, s1 = 0.f;
        #pragma unroll
        for (int gg = 0; gg < 4; ++gg) { s0 += red[gg][c0]; s1 += red[gg][c1]; }
        float o0 = fmaxf(s0 + b1[c0], 0.f);
        float o1 = fmaxf(s1 + b1[c1], 0.f);
        h1su[(size_t)d * 384 + t] = packh(o0, o1);
    }
}

// ---------------- GAT layer2 aggregate: 384 thr = 4 groups x (2 br x 48) -------------
__global__ void k_gat_agg2(const uint4* __restrict__ h2g4, const float* __restrict__ w_csr,
                           const float* __restrict__ w_self, const int* __restrict__ rp,
                           const int* __restrict__ cs, const float* __restrict__ bmu,
                           const float* __restrict__ blv, float* __restrict__ mt_gat, int E3) {
    int d = blockIdx.x;
    int t = threadIdx.x;                          // 384
    int g = t / 96, lr = t - g * 96;              // 4 groups
    int br = lr / 48, li = lr - br * 48;          // branch row = 48 uint4 (384 fp16)
    int c = li * 8;                               // fp col 0..383 within branch
    int mt = c >= 192 ? 1 : 0;
    int cm = c - mt * 192;
    int hd = cm >> 6;
    const float* wc = w_csr + (size_t)(br * 2 + mt) * E3;
    const uint4* hp = h2g4 + (size_t)br * NN * 48;
    float a[8] = {0.f, 0.f, 0.f, 0.f, 0.f, 0.f, 0.f, 0.f};
    if (g == 0) {
        float ws = w_self[(size_t)(br * 2 + mt) * NN * 3 + d * 3 + hd];
        uint4 sv = hp[(size_t)d * 48 + li];
        acc8(a, sv, ws);
    }
    int e0 = rp[d], e1 = rp[d + 1];
    int j = e0 + g;
    for (; j + 4 < e1; j += 8) {
        int s0 = cs[j], s1 = cs[j + 4];
        float w0 = wc[(size_t)j * 3 + hd];
        float w1 = wc[(size_t)(j + 4) * 3 + hd];
        uint4 v0 = hp[(size_t)s0 * 48 + li];
        uint4 v1 = hp[(size_t)s1 * 48 + li];
        acc8(a, v0, w0);
        acc8(a, v1, w1);
    }
    if (j < e1) {
        int s = cs[j];
        float w = wc[(size_t)j * 3 + hd];
        uint4 v = hp[(size_t)s * 48 + li];
        acc8(a, v, w);
    }
    __shared__ float red[4][768];                 // br*384 + c
    #pragma unroll
    for (int i = 0; i < 8; ++i) red[g][br * 384 + c + i] = a[i];
    __syncthreads();
    if (t < 256) {
        int obr = t >> 7, omt = (t >> 6) & 1, dd2 = t & 63;
        int base = obr * 384 + omt * 192;
        float tot = 0.f;
        #pragma unroll
        for (int gg = 0; gg < 4; ++gg)
            tot += red[gg][base + dd2] + red[gg][base + 64 + dd2] + red[gg][base + 128 + dd2];
        const float* bias = omt ? blv : bmu;
        float v = tot * (1.f / 3.f) + bias[obr * 64 + dd2];
        mt_gat[((size_t)(obr * 2 + omt) * NN + d) * 64 + dd2] = v;
    }
}

// ---------------- finalize: bias, z, 4-way max, outputs + split-fp16 z2 -------------
__global__ void k_finalize(const float* __restrict__ muv_gcn, const float* __restrict__ gcn_bmu,
                           const float* __restrict__ gcn_blv, const float* __restrict__ mt_gat,
                           const float* __restrict__ eps_gcn, const float* __restrict__ eps_gat,
                           float* __restrict__ mu_o, float* __restrict__ lv_o,
                           unsigned short* __restrict__ z2) {
    int i = blockIdx.x * 256 + threadIdx.x;       // NN*64
    int d = i >> 6, c = i & 63;
    const size_t NN64 = (size_t)NN * 64;
    float mu, lv, zm;
    {
        float m = muv_gcn[(size_t)d * 128 + c] + gcn_bmu[c];
        float l = muv_gcn[(size_t)d * 128 + 64 + c] + gcn_blv[c];
        float z = m + eps_gcn[i] * __expf(l);
        mu = m; lv = l; zm = z;
    }
    {
        float m = muv_gcn[NN64 * 2 + (size_t)d * 128 + c] + gcn_bmu[64 + c];
        float l = muv_gcn[NN64 * 2 + (size_t)d * 128 + 64 + c] + gcn_blv[64 + c];
        float z = m + eps_gcn[NN64 + i] * __expf(l);
        mu = fmaxf(mu, m); lv = fmaxf(lv, l); zm = fmaxf(zm, z);
    }
    #pragma unroll
    for (int br = 0; br < 2; ++br) {
        float m = mt_gat[(size_t)(br * 2 + 0) * NN64 + i];
        float l = mt_gat[(size_t)(br * 2 + 1) * NN64 + i];
        float z = m + eps_gat[(size_t)br * NN64 + i] * __expf(l);
        mu = fmaxf(mu, m); lv = fmaxf(lv, l); zm = fmaxf(zm, z);
    }
    mu_o[i] = mu;
    lv_o[i] = lv;
    unsigned short hh, ll;
    splith(zm, hh, ll);
    z2[(size_t)d * 128 + c] = hh;
    z2[(size_t)d * 128 + 64 + c] = ll;
}

extern "C" void kernel_launch(void* const* d_in, const int* in_sizes, int n_in,
                              void* d_out, int out_size, void* d_ws, size_t ws_size,
                              hipStream_t stream) {
    const float* x  = (const float*)d_in[0];
    const int*   ei = (const int*)d_in[1];
    const int E = in_sizes[1] / 2;
    const int E3 = E * 3;
    const int* src = ei;
    const int* dst = ei + E;

    const float* gcn_W1  = (const float*)d_in[2];
    const float* gcn_b1  = (const float*)d_in[3];
    const float* gcn_Wmu = (const float*)d_in[4];
    const float* gcn_bmu = (const float*)d_in[5];
    const float* gcn_Wlv = (const float*)d_in[6];
    const float* gcn_blv = (const float*)d_in[7];
    const float* gat_W1  = (const float*)d_in[8];
    const float* gat_as1 = (const float*)d_in[9];
    const float* gat_ad1 = (const float*)d_in[10];
    const float* gat_b1  = (const float*)d_in[11];
    const float* gat_Wmu = (const float*)d_in[12];
    const float* gat_asmu= (const float*)d_in[13];
    const float* gat_admu= (const float*)d_in[14];
    const float* gat_bmu = (const float*)d_in[15];
    const float* gat_Wlv = (const float*)d_in[16];
    const float* gat_aslv= (const float*)d_in[17];
    const float* gat_adlv= (const float*)d_in[18];
    const float* gat_blv = (const float*)d_in[19];
    const float* eps_gcn = (const float*)d_in[20];
    const float* eps_gat = (const float*)d_in[21];

    // ---- workspace carve ----
    char* p = (char*)d_ws;
    auto alloc = [&](size_t bytes) {
        void* r = (void*)p;
        p += (bytes + 255) & ~(size_t)255;
        return r;
    };
    int*   cnt     = (int*)alloc((size_t)NN * 4);
    int*   cursor  = (int*)alloc((size_t)NN * 4);
    int*   row_ptr = (int*)alloc((size_t)(NN + 1) * 4);
    int*   csr_src = (int*)alloc((size_t)E * 4);
    float* dinv    = (float*)alloc((size_t)NN * 4);
    float* as_n1   = (float*)alloc((size_t)2 * NN * 3 * 4);
    float* ad_n1   = (float*)alloc((size_t)2 * NN * 3 * 4);
    float* wself1  = (float*)alloc((size_t)2 * NN * 3 * 4);
    float* wcsr1   = (float*)alloc((size_t)2 * E3 * 4);
    float* as_n2   = (float*)alloc((size_t)4 * NN * 3 * 4);
    float* ad_n2   = (float*)alloc((size_t)4 * NN * 3 * 4);
    float* wself2  = (float*)alloc((size_t)4 * NN * 3 * 4);
    float* wcsr2   = (float*)alloc((size_t)4 * E3 * 4);
    unsigned short* x2h      = (unsigned short*)alloc((size_t)NN * 512 * 2);
    unsigned short* wt_gcn1  = (unsigned short*)alloc((size_t)256 * 512 * 2);
    unsigned short* wt_gcnmuv= (unsigned short*)alloc((size_t)2 * 128 * 128 * 2);
    unsigned short* wt_gat1  = (unsigned short*)alloc((size_t)768 * 512 * 2);
    unsigned short* wt_gatmuv= (unsigned short*)alloc((size_t)2 * 384 * 384 * 2);
    unsigned short* xwb  = (unsigned short*)alloc((size_t)NN * 768 * 2);  // GCN uses ld 256
    unsigned short* hb   = (unsigned short*)alloc((size_t)NN * 256 * 2);
    unsigned short* hA   = (unsigned short*)alloc((size_t)NN * 256 * 2);
    float* muv_gcn = (float*)alloc((size_t)2 * NN * 128 * 4);
    unsigned short* h1s  = (unsigned short*)alloc((size_t)NN * 768 * 2);
    unsigned short* h2gb = (unsigned short*)alloc((size_t)2 * NN * 384 * 2);
    float* mt_gat  = (float*)alloc((size_t)4 * NN * 64 * 4);
    unsigned short* z2 = (unsigned short*)alloc((size_t)NN * 128 * 2);

    float* adj  = (float*)d_out;
    float* mu_o = adj + (size_t)NN * NN;
    float* lv_o = mu_o + (size_t)NN * 64;

    // ---- CSR build ----
    k_zero<<<(2 * NN + 255) / 256, 256, 0, stream>>>(cnt, 2 * NN);
    k_count<<<(E + 255) / 256, 256, 0, stream>>>(dst, cnt, E);
    k_dinv<<<(NN + 255) / 256, 256, 0, stream>>>(cnt, dinv);
    k_scan<<<1, 1024, 0, stream>>>(cnt, row_ptr);
    k_fill<<<(E + 255) / 256, 256, 0, stream>>>(src, dst, row_ptr, cursor, csr_src, E);

    // ---- precision prep (fp16) ----
    k_cvt_x<<<NN * 512 / 4 / 256, 256, 0, stream>>>(x, x2h);
    k_wT<<<dim3(16, 4, 2), 256, 0, stream>>>(gcn_W1, wt_gcn1, 512, 128, 0, 0, 128);
    k_wT<<<dim3(4, 2, 2), 256, 0, stream>>>(gcn_Wmu, wt_gcnmuv, 128, 64, (size_t)128 * 128, 0, 0);
    k_wT<<<dim3(4, 2, 2), 256, 0, stream>>>(gcn_Wlv, wt_gcnmuv, 128, 64, (size_t)128 * 128, 64, 0);
    k_wT<<<dim3(16, 12, 2), 256, 0, stream>>>(gat_W1, wt_gat1, 512, 384, 0, 0, 384);
    k_wT<<<dim3(12, 6, 2), 256, 0, stream>>>(gat_Wmu, wt_gatmuv, 384, 192, (size_t)384 * 384, 0, 0);
    k_wT<<<dim3(12, 6, 2), 256, 0, stream>>>(gat_Wlv, wt_gatmuv, 384, 192, (size_t)384 * 384, 192, 0);

    // ---- GCN (both branches batched) ----
    // g1: xwb[:, :256] = fp16(x2h @ wt_gcn1)  (K=512, N=256), ldc=256
    k_gemm2<1, 2><<<dim3(64, 4, 1), 256, 0, stream>>>(x2h, 0, 512, wt_gcn1, 0, 512,
                                                      xwb, 0, 256, 512);
    k_gcn_agg<1><<<NN, 256, 0, stream>>>((const uint4*)xwb, dinv, row_ptr, csr_src,
                                         gcn_b1, (unsigned int*)hb);
    k_gcn_agg<0><<<NN, 256, 0, stream>>>((const uint4*)hb, dinv, row_ptr, csr_src,
                                         nullptr, (unsigned int*)hA);
    // g2: muv[z] = hA[z] @ wt_gcnmuv[z]  (K=128, N=128), fp32 out
    k_gemm2<1, 0><<<dim3(64, 2, 2), 256, 0, stream>>>(hA, 128, 256, wt_gcnmuv,
                                                      (size_t)128 * 128, 128,
                                                      muv_gcn, (size_t)NN * 128, 128, 128);

    // ---- GAT (both branches batched) ----
    // G1: xwb = fp16(x2h @ wt_gat1)  (K=512, N=768)
    k_gemm2<1, 2><<<dim3(64, 12, 1), 256, 0, stream>>>(x2h, 0, 512, wt_gat1, 0, 512,
                                                       xwb, 0, 768, 512);
    k_gat_log1<<<dim3(NN, 1, 2), 192, 0, stream>>>((const unsigned int*)xwb, gat_as1,
                                                   gat_ad1, as_n1, ad_n1);
    k_gat_attn<<<dim3(NN, 1, 2), 192, 0, stream>>>(as_n1, ad_n1, row_ptr, csr_src,
                                                   wcsr1, wself1, E3);
    k_gat_agg1<<<NN, 384, 0, stream>>>((const uint4*)xwb, wcsr1, wself1, row_ptr, csr_src,
                                       gat_b1, (unsigned int*)h1s, E3);
    // G2: h2gb[z] = fp16(h1s[z] @ wt_gatmuv[z])  (K=384, N=384)
    k_gemm2<1, 2><<<dim3(64, 6, 2), 256, 0, stream>>>(h1s, 384, 768, wt_gatmuv,
                                                      (size_t)384 * 384, 384,
                                                      h2gb, (size_t)NN * 384, 384, 384);
    k_gat_log2<<<dim3(NN, 1, 4), 192, 0, stream>>>(h2gb, gat_asmu, gat_aslv, gat_admu,
                                                   gat_adlv, as_n2, ad_n2);
    k_gat_attn<<<dim3(NN, 1, 4), 192, 0, stream>>>(as_n2, ad_n2, row_ptr, csr_src,
                                                   wcsr2, wself2, E3);
    k_gat_agg2<<<NN, 384, 0, stream>>>((const uint4*)h2gb, wcsr2, wself2, row_ptr, csr_src,
                                       gat_bmu, gat_blv, mt_gat, E3);

    // ---- finalize + adjacency (fp16 hi/lo 3-term for accuracy) ----
    k_finalize<<<NN * 64 / 256, 256, 0, stream>>>(muv_gcn, gcn_bmu, gcn_blv, mt_gat,
                                                  eps_gcn, eps_gat, mu_o, lv_o, z2);
    k_gemm2<3, 1><<<dim3(64, 128, 1), 256, 0, stream>>>(z2, 0, 128, z2, 0, 128,
                                                        adj, 0, NN, 64);
}